// Round 1
// baseline (433.061 us; speedup 1.0000x reference)
//
#include <hip/hip_runtime.h>
#include <math.h>

#define BATCH 8
#define CH    512
#define NPIX  1024
#define NH    4

// ---------------------------------------------------------------------------
// Kernel 1: QKV projection.  Per batch: [768 x 512] @ [512 x 1024].
// Rows 0..127 -> Q (Wq), 128..255 -> K (Wk), 256..767 -> V (Wv).
// 64x64 output tile per block, 256 threads, 4x4 per-thread micro-tile.
// ---------------------------------------------------------------------------
__global__ __launch_bounds__(256) void qkv_proj(
    const float* __restrict__ x,
    const float* __restrict__ Wq, const float* __restrict__ bq,
    const float* __restrict__ Wk, const float* __restrict__ bk,
    const float* __restrict__ Wv, const float* __restrict__ bv,
    float* __restrict__ Q, float* __restrict__ K, float* __restrict__ V)
{
    __shared__ float As[64][17];   // [row][k]  pad 17 to break store conflicts
    __shared__ float Bs[16][64];   // [k][pixel]

    const int t  = threadIdx.x;
    const int tx = t & 15;
    const int ty = t >> 4;
    const int p0 = blockIdx.x * 64;
    const int m0 = blockIdx.y * 64;
    const int b  = blockIdx.z;

    const float* W; const float* bias; float* O;
    if (m0 < 128)      { W = Wq + (size_t)m0       * CH; bias = bq + m0;        O = Q + ((size_t)b*128 +  m0       ) * NPIX; }
    else if (m0 < 256) { W = Wk + (size_t)(m0-128) * CH; bias = bk + (m0-128);  O = K + ((size_t)b*128 + (m0-128) ) * NPIX; }
    else               { W = Wv + (size_t)(m0-256) * CH; bias = bv + (m0-256);  O = V + ((size_t)b*512 + (m0-256) ) * NPIX; }

    const float* X = x + (size_t)b * CH * NPIX;

    float acc[4][4] = {};

    const int ai = t >> 4;   // 0..15  (row group for A loads)
    const int aj = t & 15;   // k within A tile
    const int bj = t >> 6;   // 0..3   (k row group for B loads)
    const int bi = t & 63;   // pixel within B tile

    for (int kk = 0; kk < CH; kk += 16) {
        __syncthreads();
        #pragma unroll
        for (int l = 0; l < 4; ++l)
            As[ai + l*16][aj] = W[(size_t)(ai + l*16) * CH + kk + aj];
        #pragma unroll
        for (int l = 0; l < 4; ++l)
            Bs[bj + l*4][bi] = X[(size_t)(kk + bj + l*4) * NPIX + p0 + bi];
        __syncthreads();

        #pragma unroll
        for (int k = 0; k < 16; ++k) {
            const float4 b4 = *reinterpret_cast<const float4*>(&Bs[k][tx * 4]);
            const float bb0 = b4.x, bb1 = b4.y, bb2 = b4.z, bb3 = b4.w;
            #pragma unroll
            for (int a = 0; a < 4; ++a) {
                const float av = As[ty*4 + a][k];
                acc[a][0] = fmaf(av, bb0, acc[a][0]);
                acc[a][1] = fmaf(av, bb1, acc[a][1]);
                acc[a][2] = fmaf(av, bb2, acc[a][2]);
                acc[a][3] = fmaf(av, bb3, acc[a][3]);
            }
        }
    }

    #pragma unroll
    for (int a = 0; a < 4; ++a) {
        const int row = ty*4 + a;
        const float bb = bias[row];
        float4 o;
        o.x = acc[a][0] + bb; o.y = acc[a][1] + bb;
        o.z = acc[a][2] + bb; o.w = acc[a][3] + bb;
        *reinterpret_cast<float4*>(&O[(size_t)row * NPIX + p0 + tx*4]) = o;
    }
}

// ---------------------------------------------------------------------------
// Kernel 2: fused flash attention per (b, head, 64-row n-tile).
// Q[32 x 64] persistent in LDS; loop over 16 m-tiles of 64:
//   S = (Q^T K)/sqrt(128) -> online softmax (shfl row reduce) -> P in LDS
//   accO[n][c] += P[n][m] * V[c][m]   (V staged transposed, XOR-swizzled)
// Epilogue: normalize by row sum, LDS transpose, coalesced gamma*o + x.
// LDS: 2048+2048+8192+4096 floats = exactly 64 KB.
// ---------------------------------------------------------------------------
__global__ __launch_bounds__(256) void attn_fused(
    const float* __restrict__ Q, const float* __restrict__ K,
    const float* __restrict__ V, const float* __restrict__ x,
    const float* __restrict__ gamma, float* __restrict__ out)
{
    __shared__ float Qs[32][64];    // [d][n]
    __shared__ float Ks[32][64];    // [d][m]
    __shared__ float VsT[64][128];  // [m][c]  (columns XOR-swizzled by m&31)
    __shared__ float Ps[64][64];    // [n][m]

    const int t  = threadIdx.x;
    const int tx = t & 15;
    const int ty = t >> 4;
    const int n0 = blockIdx.x * 64;
    const int h  = blockIdx.y;
    const int b  = blockIdx.z;

    const float* Qb = Q + ((size_t)b*NH + h) * 32  * NPIX;
    const float* Kb = K + ((size_t)b*NH + h) * 32  * NPIX;
    const float* Vb = V + ((size_t)b*NH + h) * 128 * NPIX;

    // load Q tile [32][64] (coalesced along n)
    #pragma unroll
    for (int l = 0; l < 8; ++l) {
        const int idx = t + l*256;
        Qs[idx >> 6][idx & 63] = Qb[(size_t)(idx >> 6) * NPIX + n0 + (idx & 63)];
    }

    float accO[4][8] = {};
    float mrow[4] = {-INFINITY, -INFINITY, -INFINITY, -INFINITY};
    float lrow[4] = {0.f, 0.f, 0.f, 0.f};
    const float rscale = 0.088388347648318447f; // 1/sqrt(128)

    for (int m0 = 0; m0 < NPIX; m0 += 64) {
        __syncthreads();   // previous PV done; Qs ready (iter 0)
        #pragma unroll
        for (int l = 0; l < 8; ++l) {
            const int idx = t + l*256;
            Ks[idx >> 6][idx & 63] = Kb[(size_t)(idx >> 6) * NPIX + m0 + (idx & 63)];
        }
        // V tile transposed into LDS; XOR swizzle kills the 32-way transpose
        // store conflict (lanes vary in m=row, write col c^(m&31): all banks hit)
        #pragma unroll
        for (int l = 0; l < 32; ++l) {
            const int idx = t + l*256;
            const int c = idx >> 6, j = idx & 63;
            VsT[j][c ^ (j & 31)] = Vb[(size_t)c * NPIX + m0 + j];
        }
        __syncthreads();

        // S-GEMM: thread owns rows n=4ty+a, cols m=4tx+j
        float s[4][4] = {};
        #pragma unroll
        for (int d = 0; d < 32; ++d) {
            const float4 q4 = *reinterpret_cast<const float4*>(&Qs[d][ty*4]);
            const float4 k4 = *reinterpret_cast<const float4*>(&Ks[d][tx*4]);
            const float qa[4] = {q4.x, q4.y, q4.z, q4.w};
            const float kb4[4] = {k4.x, k4.y, k4.z, k4.w};
            #pragma unroll
            for (int a = 0; a < 4; ++a)
                #pragma unroll
                for (int j = 0; j < 4; ++j)
                    s[a][j] = fmaf(qa[a], kb4[j], s[a][j]);
        }

        // online softmax; rows owned by the 16 lanes sharing ty -> shfl width 16
        #pragma unroll
        for (int a = 0; a < 4; ++a) {
            float p[4];
            float rm = -INFINITY;
            #pragma unroll
            for (int j = 0; j < 4; ++j) { s[a][j] *= rscale; rm = fmaxf(rm, s[a][j]); }
            #pragma unroll
            for (int off = 1; off < 16; off <<= 1)
                rm = fmaxf(rm, __shfl_xor(rm, off, 16));
            const float mnew = fmaxf(mrow[a], rm);
            const float f = __expf(mrow[a] - mnew);   // exp(-inf)=0 on first tile
            float ps = 0.f;
            #pragma unroll
            for (int j = 0; j < 4; ++j) { p[j] = __expf(s[a][j] - mnew); ps += p[j]; }
            #pragma unroll
            for (int off = 1; off < 16; off <<= 1)
                ps += __shfl_xor(ps, off, 16);
            lrow[a] = lrow[a] * f + ps;
            mrow[a] = mnew;
            #pragma unroll
            for (int cc = 0; cc < 8; ++cc) accO[a][cc] *= f;
            #pragma unroll
            for (int j = 0; j < 4; ++j) Ps[ty*4 + a][tx*4 + j] = p[j];
        }
        __syncthreads();

        // PV: accO[n=4ty+a][c=tx+16cc] += P[n][m] * V[c][m]
        #pragma unroll 4
        for (int m = 0; m < 64; ++m) {
            const int sw = m & 31;
            float pv[4];
            #pragma unroll
            for (int a = 0; a < 4; ++a) pv[a] = Ps[ty*4 + a][m];
            #pragma unroll
            for (int cc = 0; cc < 8; ++cc) {
                const float vv = VsT[m][(tx + 16*cc) ^ sw];
                #pragma unroll
                for (int a = 0; a < 4; ++a)
                    accO[a][cc] = fmaf(pv[a], vv, accO[a][cc]);
            }
        }
    }

    __syncthreads();
    // normalize + stash tile in LDS (reuse VsT as On[n][c], no swizzle)
    #pragma unroll
    for (int a = 0; a < 4; ++a) {
        const float inv = 1.0f / lrow[a];
        #pragma unroll
        for (int cc = 0; cc < 8; ++cc)
            VsT[ty*4 + a][tx + 16*cc] = accO[a][cc] * inv;
    }
    __syncthreads();

    const float g = gamma[0];
    float*       outB = out + ((size_t)b*CH + h*128) * NPIX;
    const float* xB   = x   + ((size_t)b*CH + h*128) * NPIX;
    #pragma unroll
    for (int l = 0; l < 32; ++l) {
        const int idx = t + l*256;
        const int c = idx >> 6, n = idx & 63;   // consecutive t -> consecutive n
        const size_t o = (size_t)c * NPIX + n0 + n;
        outB[o] = fmaf(g, VsT[n][c], xB[o]);
    }
}

// ---------------------------------------------------------------------------
extern "C" void kernel_launch(void* const* d_in, const int* in_sizes, int n_in,
                              void* d_out, int out_size, void* d_ws, size_t ws_size,
                              hipStream_t stream)
{
    const float* x     = (const float*)d_in[0];
    const float* Wq    = (const float*)d_in[1];
    const float* bq    = (const float*)d_in[2];
    const float* Wk    = (const float*)d_in[3];
    const float* bk    = (const float*)d_in[4];
    const float* Wv    = (const float*)d_in[5];
    const float* bv    = (const float*)d_in[6];
    const float* gamma = (const float*)d_in[7];
    float* out = (float*)d_out;

    float* Q = (float*)d_ws;                       //  8*128*1024 floats (4 MB)
    float* K = Q + (size_t)BATCH * 128 * NPIX;     //  4 MB
    float* V = K + (size_t)BATCH * 128 * NPIX;     // 16 MB   (total 24 MB of ws)

    qkv_proj<<<dim3(NPIX/64, 768/64, BATCH), 256, 0, stream>>>(
        x, Wq, bq, Wk, bk, Wv, bv, Q, K, V);
    attn_fused<<<dim3(NPIX/64, NH, BATCH), 256, 0, stream>>>(
        Q, K, V, x, gamma, out);
}

// Round 2
// 100.761 us; speedup vs baseline: 4.2979x; 4.2979x over previous
//
#include <hip/hip_runtime.h>
#include <math.h>

#define BATCH 8
#define CH    512
#define NPIX  1024
#define NH    4

typedef __attribute__((ext_vector_type(8))) short bf16x8;
typedef __attribute__((ext_vector_type(4))) float f32x4;

// 1/sqrt(128) * log2(e): folded into Wq/bq so softmax = exp2(s - m)
#define QSC (0.088388347648318447f * 1.4426950408889634f)

__device__ inline unsigned short f2bf_rne(float f) {
    unsigned int u = __float_as_uint(f);
    return (unsigned short)((u + 0x7FFFu + ((u >> 16) & 1u)) >> 16);
}
__device__ inline unsigned int pack_bf2_trunc(float a, float b) {
    return (__float_as_uint(a) >> 16) | (__float_as_uint(b) & 0xFFFF0000u);
}

// ---------------------------------------------------------------------------
// Prep A: X [b][c][n] fp32 -> XT [b][n][c] bf16   (64x64 LDS tiles, pad 65)
// ---------------------------------------------------------------------------
__global__ __launch_bounds__(256) void x_transpose(
    const float* __restrict__ x, unsigned short* __restrict__ XT)
{
    __shared__ float S[64][65];
    const int t = threadIdx.x;
    const int a = t & 15, g = t >> 4;
    const int n0 = blockIdx.x * 64, c0 = blockIdx.y * 64, b = blockIdx.z;
    const float* xb = x + ((size_t)b * CH + c0) * NPIX + n0;
    #pragma unroll
    for (int i = 0; i < 4; ++i) {
        const int c = g + 16 * i;
        const float4 v = *(const float4*)&xb[(size_t)c * NPIX + 4 * a];
        S[c][4*a+0] = v.x; S[c][4*a+1] = v.y; S[c][4*a+2] = v.z; S[c][4*a+3] = v.w;
    }
    __syncthreads();
    unsigned short* ob = XT + ((size_t)b * NPIX + n0) * CH + c0;
    #pragma unroll
    for (int i = 0; i < 4; ++i) {
        const int n = g + 16 * i;
        const unsigned int w0 = pack_bf2_trunc(0.f, 0.f) * 0u  // keep simple below
                              | 0u;
        unsigned short b0 = f2bf_rne(S[4*a+0][n]);
        unsigned short b1 = f2bf_rne(S[4*a+1][n]);
        unsigned short b2 = f2bf_rne(S[4*a+2][n]);
        unsigned short b3 = f2bf_rne(S[4*a+3][n]);
        uint2 st;
        st.x = (unsigned int)b0 | ((unsigned int)b1 << 16);
        st.y = (unsigned int)b2 | ((unsigned int)b3 << 16);
        *(uint2*)&ob[(size_t)n * CH + 4 * a] = st;
    }
}

// ---------------------------------------------------------------------------
// Prep B: W fp32 -> Wb [768][512] bf16; rows 0..128 = Wq * QSC, 128..256 = Wk,
// 256..768 = Wv.
// ---------------------------------------------------------------------------
__global__ __launch_bounds__(256) void w_convert(
    const float* __restrict__ Wq, const float* __restrict__ Wk,
    const float* __restrict__ Wv, unsigned short* __restrict__ Wb)
{
    const size_t idx = ((size_t)blockIdx.x * 256 + threadIdx.x) * 4;  // < 768*512
    float4 v;
    if (idx < 65536) {
        v = *(const float4*)&Wq[idx];
        v.x *= QSC; v.y *= QSC; v.z *= QSC; v.w *= QSC;
    } else if (idx < 131072) {
        v = *(const float4*)&Wk[idx - 65536];
    } else {
        v = *(const float4*)&Wv[idx - 131072];
    }
    uint2 st;
    st.x = (unsigned int)f2bf_rne(v.x) | ((unsigned int)f2bf_rne(v.y) << 16);
    st.y = (unsigned int)f2bf_rne(v.z) | ((unsigned int)f2bf_rne(v.w) << 16);
    *(uint2*)&Wb[idx] = st;
}

// ---------------------------------------------------------------------------
// QKV projection, MFMA, LDS-free mainloop.
// Per wave: 32 o x 64 n tile. A-frags from Wb[o][k], B-frags from XT[n][k],
// both direct coalesced global dwordx4. Epilogue: Q/K -> LDS swizzled
// transpose -> QT/KT[bh][n][32] bf16; V -> direct stores V[bh][c][m] bf16.
// ---------------------------------------------------------------------------
__global__ __launch_bounds__(256, 2) void qkv_proj(
    const unsigned short* __restrict__ XT, const unsigned short* __restrict__ Wb,
    const float* __restrict__ bq, const float* __restrict__ bk,
    const float* __restrict__ bv,
    unsigned short* __restrict__ QT, unsigned short* __restrict__ KT,
    unsigned short* __restrict__ V)
{
    __shared__ unsigned short OT[4][2048];   // per-wave 64n x 32o, 8B-granule swizzle
    const int t = threadIdx.x, w = t >> 6, l = t & 63;
    const int lo = l & 15, hi = l >> 4;
    const int b = blockIdx.z;
    const int o0 = blockIdx.y * 64 + (w >> 1) * 32;
    const int n0 = blockIdx.x * 128 + (w & 1) * 64;

    const unsigned short* Ab = Wb + (size_t)(o0 + lo) * CH + hi * 8;
    const unsigned short* Bb = XT + ((size_t)b * NPIX + n0 + lo) * CH + hi * 8;

    f32x4 acc[2][4] = {};
    #pragma unroll 4
    for (int k = 0; k < CH; k += 32) {
        bf16x8 af[2], bf[4];
        #pragma unroll
        for (int i = 0; i < 2; ++i) af[i] = *(const bf16x8*)(Ab + i * 8192 + k);
        #pragma unroll
        for (int j = 0; j < 4; ++j) bf[j] = *(const bf16x8*)(Bb + j * 8192 + k);
        #pragma unroll
        for (int i = 0; i < 2; ++i)
            #pragma unroll
            for (int j = 0; j < 4; ++j)
                acc[i][j] = __builtin_amdgcn_mfma_f32_16x16x32_bf16(af[i], bf[j], acc[i][j], 0, 0, 0);
    }

    // bias per output row (rows: o = o0 + i*16 + hi*4 + r)
    float bias[2][4];
    #pragma unroll
    for (int i = 0; i < 2; ++i)
        #pragma unroll
        for (int r = 0; r < 4; ++r) {
            const int orow = o0 + i * 16 + hi * 4 + r;
            if (o0 < 128)      bias[i][r] = bq[orow] * QSC;
            else if (o0 < 256) bias[i][r] = bk[orow - 128];
            else               bias[i][r] = bv[orow - 256];
        }

    if (o0 < 256) {
        const bool isQ = (o0 < 128);
        const int hh = (o0 & 127) >> 5;
        // write swizzled OT[n][o]
        #pragma unroll
        for (int i = 0; i < 2; ++i)
            #pragma unroll
            for (int j = 0; j < 4; ++j) {
                const int nl = j * 16 + lo;
                const int og = i * 4 + hi;          // o-granule (4 elems)
                unsigned short v0 = f2bf_rne(acc[i][j][0] + bias[i][0]);
                unsigned short v1 = f2bf_rne(acc[i][j][1] + bias[i][1]);
                unsigned short v2 = f2bf_rne(acc[i][j][2] + bias[i][2]);
                unsigned short v3 = f2bf_rne(acc[i][j][3] + bias[i][3]);
                uint2 st;
                st.x = (unsigned int)v0 | ((unsigned int)v1 << 16);
                st.y = (unsigned int)v2 | ((unsigned int)v3 << 16);
                *(uint2*)&OT[w][nl * 32 + ((og ^ (nl & 7)) << 2)] = st;
            }
        unsigned short* outp = (isQ ? QT : KT) + (size_t)(b * NH + hh) * NPIX * 32;
        #pragma unroll
        for (int it = 0; it < 4; ++it) {
            const int nl = (l >> 2) + 16 * it, seg = l & 3;
            const int g0 = (2 * seg) ^ (nl & 7);
            const int g1 = (2 * seg + 1) ^ (nl & 7);
            const uint2 p0 = *(uint2*)&OT[w][nl * 32 + g0 * 4];
            const uint2 p1 = *(uint2*)&OT[w][nl * 32 + g1 * 4];
            uint4 st; st.x = p0.x; st.y = p0.y; st.z = p1.x; st.w = p1.y;
            *(uint4*)&outp[(size_t)(n0 + nl) * 32 + seg * 8] = st;
        }
    } else {
        const int hh = (o0 - 256) >> 7;
        const int cb = (o0 - 256) & 127;
        unsigned short* vb = V + (size_t)(b * NH + hh) * 128 * NPIX;
        #pragma unroll
        for (int i = 0; i < 2; ++i)
            #pragma unroll
            for (int j = 0; j < 4; ++j)
                #pragma unroll
                for (int r = 0; r < 4; ++r) {
                    const int c = cb + i * 16 + hi * 4 + r;
                    const int n = n0 + j * 16 + lo;
                    vb[(size_t)c * NPIX + n] = f2bf_rne(acc[i][j][r] + bias[i][r]);
                }
    }
}

// ---------------------------------------------------------------------------
// Fused flash attention, MFMA. grid (8 ntiles, 32 bh), 4 independent waves
// per block, 32 q-rows per wave, KV tile = 64.
// S^T = mfma(K-frag, Q-frag): lane owns one softmax row (n = lane&15 per jnf).
// ---------------------------------------------------------------------------
__global__ __launch_bounds__(256, 1) void attn(
    const unsigned short* __restrict__ QT, const unsigned short* __restrict__ KT,
    const unsigned short* __restrict__ V,  const float* __restrict__ x,
    const float* __restrict__ gamma, float* __restrict__ out)
{
    __shared__ float SM[4][2112];   // per-wave union: Ps (1024 f) / Ot (64*33 f)
    const int t = threadIdx.x, w = t >> 6, l = t & 63;
    const int lo = l & 15, hi = l >> 4;
    const int bh = blockIdx.y;
    const int n0w = blockIdx.x * 128 + w * 32;

    unsigned short* Ps = (unsigned short*)&SM[w][0];
    float* Ot = &SM[w][0];

    const unsigned short* Qb = QT + (size_t)bh * NPIX * 32;
    const unsigned short* Kb = KT + (size_t)bh * NPIX * 32;
    const unsigned short* Vb = V + (size_t)bh * 128 * NPIX;

    bf16x8 qf[2];
    #pragma unroll
    for (int j = 0; j < 2; ++j)
        qf[j] = *(const bf16x8*)&Qb[(size_t)(n0w + j * 16 + lo) * 32 + hi * 8];

    f32x4 of[2][8] = {};
    float mrow[2] = {-INFINITY, -INFINITY};
    float lrow[2] = {0.f, 0.f};

    for (int m0 = 0; m0 < NPIX; m0 += 64) {
        bf16x8 kf[4];
        #pragma unroll
        for (int i = 0; i < 4; ++i)
            kf[i] = *(const bf16x8*)&Kb[(size_t)(m0 + i * 16 + lo) * 32 + hi * 8];
        // V frags issued early: latency hides under softmax
        bf16x8 vf[8][2];
        #pragma unroll
        for (int c = 0; c < 8; ++c)
            #pragma unroll
            for (int ks = 0; ks < 2; ++ks)
                vf[c][ks] = *(const bf16x8*)&Vb[(size_t)(c * 16 + lo) * NPIX + m0 + ks * 32 + hi * 8];

        const f32x4 zero = {0.f, 0.f, 0.f, 0.f};
        f32x4 sf[4][2];
        #pragma unroll
        for (int i = 0; i < 4; ++i)
            #pragma unroll
            for (int j = 0; j < 2; ++j)
                sf[i][j] = __builtin_amdgcn_mfma_f32_16x16x32_bf16(kf[i], qf[j], zero, 0, 0, 0);

        float fsc[2];
        #pragma unroll
        for (int j = 0; j < 2; ++j) {
            // row max over 16 local m-values (rows m = i*16 + hi*4 + r, col n = j*16+lo)
            float mx = sf[0][j][0];
            #pragma unroll
            for (int i = 0; i < 4; ++i)
                #pragma unroll
                for (int r = 0; r < 4; ++r) mx = fmaxf(mx, sf[i][j][r]);
            mx = fmaxf(mx, __shfl_xor(mx, 16));
            mx = fmaxf(mx, __shfl_xor(mx, 32));
            const float mn = fmaxf(mrow[j], mx);
            fsc[j] = __builtin_amdgcn_exp2f(mrow[j] - mn);
            mrow[j] = mn;
            float ps = 0.f;
            const int nl = j * 16 + lo;
            #pragma unroll
            for (int i = 0; i < 4; ++i) {
                const float p0 = __builtin_amdgcn_exp2f(sf[i][j][0] - mn);
                const float p1 = __builtin_amdgcn_exp2f(sf[i][j][1] - mn);
                const float p2 = __builtin_amdgcn_exp2f(sf[i][j][2] - mn);
                const float p3 = __builtin_amdgcn_exp2f(sf[i][j][3] - mn);
                ps += (p0 + p1) + (p2 + p3);
                const int mchunk = i * 2 + (hi >> 1);
                const int off = nl * 64 + ((mchunk ^ (nl & 7)) << 3) + ((hi & 1) << 2);
                uint2 st; st.x = pack_bf2_trunc(p0, p1); st.y = pack_bf2_trunc(p2, p3);
                *(uint2*)&Ps[off] = st;
            }
            ps += __shfl_xor(ps, 16);
            ps += __shfl_xor(ps, 32);
            lrow[j] = lrow[j] * fsc[j] + ps;
        }

        // rescale O by f for its rows (n = inf*16 + hi*4 + r)
        #pragma unroll
        for (int inf = 0; inf < 2; ++inf)
            #pragma unroll
            for (int r = 0; r < 4; ++r) {
                const float f = __shfl(fsc[inf], hi * 4 + r, 16);
                #pragma unroll
                for (int c = 0; c < 8; ++c) of[inf][c][r] *= f;
            }

        // PV: A = P from LDS, B = V frags
        bf16x8 pa[2][2];
        #pragma unroll
        for (int inf = 0; inf < 2; ++inf)
            #pragma unroll
            for (int ks = 0; ks < 2; ++ks) {
                const int nl = inf * 16 + lo;
                const int mchunk = ks * 4 + hi;
                pa[inf][ks] = *(const bf16x8*)&Ps[nl * 64 + ((mchunk ^ (nl & 7)) << 3)];
            }
        #pragma unroll
        for (int inf = 0; inf < 2; ++inf)
            #pragma unroll
            for (int c = 0; c < 8; ++c) {
                of[inf][c] = __builtin_amdgcn_mfma_f32_16x16x32_bf16(pa[inf][0], vf[c][0], of[inf][c], 0, 0, 0);
                of[inf][c] = __builtin_amdgcn_mfma_f32_16x16x32_bf16(pa[inf][1], vf[c][1], of[inf][c], 0, 0, 0);
            }
    }

    // normalization factors per O-row
    float invv[2][4];
    #pragma unroll
    for (int inf = 0; inf < 2; ++inf)
        #pragma unroll
        for (int r = 0; r < 4; ++r)
            invv[inf][r] = 1.0f / __shfl(lrow[inf], hi * 4 + r, 16);

    const float g = gamma[0];
    const int b = bh >> 2, h = bh & 3;

    #pragma unroll
    for (int half = 0; half < 2; ++half) {
        // stash half of O (64 c) transposed into Ot[c][n] (pad 33)
        #pragma unroll
        for (int inf = 0; inf < 2; ++inf)
            #pragma unroll
            for (int r = 0; r < 4; ++r) {
                const int n = inf * 16 + hi * 4 + r;
                #pragma unroll
                for (int cf = 0; cf < 4; ++cf)
                    Ot[(cf * 16 + lo) * 33 + n] = of[inf][half * 4 + cf][r] * invv[inf][r];
            }
        const size_t cbase = (size_t)b * CH + h * 128 + half * 64;
        #pragma unroll 4
        for (int cc = 0; cc < 32; ++cc) {
            const int cl = (l >> 5) + 2 * cc;
            const int n = l & 31;
            const float o = Ot[cl * 33 + n];
            const size_t gi = (cbase + cl) * NPIX + n0w + n;
            out[gi] = fmaf(g, o, x[gi]);
        }
    }
}

// ---------------------------------------------------------------------------
extern "C" void kernel_launch(void* const* d_in, const int* in_sizes, int n_in,
                              void* d_out, int out_size, void* d_ws, size_t ws_size,
                              hipStream_t stream)
{
    const float* x     = (const float*)d_in[0];
    const float* Wq    = (const float*)d_in[1];
    const float* bq    = (const float*)d_in[2];
    const float* Wk    = (const float*)d_in[3];
    const float* bk    = (const float*)d_in[4];
    const float* Wv    = (const float*)d_in[5];
    const float* bv    = (const float*)d_in[6];
    const float* gamma = (const float*)d_in[7];
    float* out = (float*)d_out;

    char* ws = (char*)d_ws;
    unsigned short* XTp = (unsigned short*)(ws);             // 8 MB
    unsigned short* Wbp = (unsigned short*)(ws + 8388608);   // 768 KB
    unsigned short* QTp = (unsigned short*)(ws + 9175040);   // 2 MB
    unsigned short* KTp = (unsigned short*)(ws + 11272192);  // 2 MB
    unsigned short* Vp  = (unsigned short*)(ws + 13369344);  // 8 MB

    x_transpose<<<dim3(16, 8, 8), 256, 0, stream>>>(x, XTp);
    w_convert<<<dim3(384), 256, 0, stream>>>(Wq, Wk, Wv, Wbp);
    qkv_proj<<<dim3(8, 12, 8), 256, 0, stream>>>(XTp, Wbp, bq, bk, bv, QTp, KTp, Vp);
    attn<<<dim3(8, 32), 256, 0, stream>>>(QTp, KTp, Vp, x, gamma, out);
}

// Round 3
// 90.902 us; speedup vs baseline: 4.7640x; 1.1085x over previous
//
#include <hip/hip_runtime.h>
#include <math.h>

#define BATCH 8
#define CH    512
#define NPIX  1024
#define NH    4

typedef __attribute__((ext_vector_type(8))) short bf16x8;
typedef __attribute__((ext_vector_type(4))) float f32x4;

// 1/sqrt(128) * log2(e): folded into Wq/bq so softmax = exp2(s - m)
#define QSC (0.088388347648318447f * 1.4426950408889634f)

__device__ inline unsigned short f2bf_rne(float f) {
    unsigned int u = __float_as_uint(f);
    return (unsigned short)((u + 0x7FFFu + ((u >> 16) & 1u)) >> 16);
}
__device__ inline unsigned int pack_bf2_trunc(float a, float b) {
    return (__float_as_uint(a) >> 16) | (__float_as_uint(b) & 0xFFFF0000u);
}

// ---------------------------------------------------------------------------
// Prep A: X [b][c][n] fp32 -> XT [b][n][c] bf16   (64x64 LDS tiles, pad 65)
// ---------------------------------------------------------------------------
__global__ __launch_bounds__(256) void x_transpose(
    const float* __restrict__ x, unsigned short* __restrict__ XT)
{
    __shared__ float S[64][65];
    const int t = threadIdx.x;
    const int a = t & 15, g = t >> 4;
    const int n0 = blockIdx.x * 64, c0 = blockIdx.y * 64, b = blockIdx.z;
    const float* xb = x + ((size_t)b * CH + c0) * NPIX + n0;
    #pragma unroll
    for (int i = 0; i < 4; ++i) {
        const int c = g + 16 * i;
        const float4 v = *(const float4*)&xb[(size_t)c * NPIX + 4 * a];
        S[c][4*a+0] = v.x; S[c][4*a+1] = v.y; S[c][4*a+2] = v.z; S[c][4*a+3] = v.w;
    }
    __syncthreads();
    unsigned short* ob = XT + ((size_t)b * NPIX + n0) * CH + c0;
    #pragma unroll
    for (int i = 0; i < 4; ++i) {
        const int n = g + 16 * i;
        unsigned short b0 = f2bf_rne(S[4*a+0][n]);
        unsigned short b1 = f2bf_rne(S[4*a+1][n]);
        unsigned short b2 = f2bf_rne(S[4*a+2][n]);
        unsigned short b3 = f2bf_rne(S[4*a+3][n]);
        uint2 st;
        st.x = (unsigned int)b0 | ((unsigned int)b1 << 16);
        st.y = (unsigned int)b2 | ((unsigned int)b3 << 16);
        *(uint2*)&ob[(size_t)n * CH + 4 * a] = st;
    }
}

// ---------------------------------------------------------------------------
// Prep B: W fp32 -> Wb [768][512] bf16; rows 0..128 = Wq * QSC, 128..256 = Wk,
// 256..768 = Wv.
// ---------------------------------------------------------------------------
__global__ __launch_bounds__(256) void w_convert(
    const float* __restrict__ Wq, const float* __restrict__ Wk,
    const float* __restrict__ Wv, unsigned short* __restrict__ Wb)
{
    const size_t idx = ((size_t)blockIdx.x * 256 + threadIdx.x) * 4;  // < 768*512
    float4 v;
    if (idx < 65536) {
        v = *(const float4*)&Wq[idx];
        v.x *= QSC; v.y *= QSC; v.z *= QSC; v.w *= QSC;
    } else if (idx < 131072) {
        v = *(const float4*)&Wk[idx - 65536];
    } else {
        v = *(const float4*)&Wv[idx - 131072];
    }
    uint2 st;
    st.x = (unsigned int)f2bf_rne(v.x) | ((unsigned int)f2bf_rne(v.y) << 16);
    st.y = (unsigned int)f2bf_rne(v.z) | ((unsigned int)f2bf_rne(v.w) << 16);
    *(uint2*)&Wb[idx] = st;
}

// ---------------------------------------------------------------------------
// QKV projection, MFMA, LDS-free mainloop (unchanged from round 2).
// ---------------------------------------------------------------------------
__global__ __launch_bounds__(256, 2) void qkv_proj(
    const unsigned short* __restrict__ XT, const unsigned short* __restrict__ Wb,
    const float* __restrict__ bq, const float* __restrict__ bk,
    const float* __restrict__ bv,
    unsigned short* __restrict__ QT, unsigned short* __restrict__ KT,
    unsigned short* __restrict__ V)
{
    __shared__ unsigned short OT[4][2048];   // per-wave 64n x 32o, 8B-granule swizzle
    const int t = threadIdx.x, w = t >> 6, l = t & 63;
    const int lo = l & 15, hi = l >> 4;
    const int b = blockIdx.z;
    const int o0 = blockIdx.y * 64 + (w >> 1) * 32;
    const int n0 = blockIdx.x * 128 + (w & 1) * 64;

    const unsigned short* Ab = Wb + (size_t)(o0 + lo) * CH + hi * 8;
    const unsigned short* Bb = XT + ((size_t)b * NPIX + n0 + lo) * CH + hi * 8;

    f32x4 acc[2][4] = {};
    #pragma unroll 4
    for (int k = 0; k < CH; k += 32) {
        bf16x8 af[2], bf[4];
        #pragma unroll
        for (int i = 0; i < 2; ++i) af[i] = *(const bf16x8*)(Ab + i * 8192 + k);
        #pragma unroll
        for (int j = 0; j < 4; ++j) bf[j] = *(const bf16x8*)(Bb + j * 8192 + k);
        #pragma unroll
        for (int i = 0; i < 2; ++i)
            #pragma unroll
            for (int j = 0; j < 4; ++j)
                acc[i][j] = __builtin_amdgcn_mfma_f32_16x16x32_bf16(af[i], bf[j], acc[i][j], 0, 0, 0);
    }

    float bias[2][4];
    #pragma unroll
    for (int i = 0; i < 2; ++i)
        #pragma unroll
        for (int r = 0; r < 4; ++r) {
            const int orow = o0 + i * 16 + hi * 4 + r;
            if (o0 < 128)      bias[i][r] = bq[orow] * QSC;
            else if (o0 < 256) bias[i][r] = bk[orow - 128];
            else               bias[i][r] = bv[orow - 256];
        }

    if (o0 < 256) {
        const bool isQ = (o0 < 128);
        const int hh = (o0 & 127) >> 5;
        #pragma unroll
        for (int i = 0; i < 2; ++i)
            #pragma unroll
            for (int j = 0; j < 4; ++j) {
                const int nl = j * 16 + lo;
                const int og = i * 4 + hi;
                unsigned short v0 = f2bf_rne(acc[i][j][0] + bias[i][0]);
                unsigned short v1 = f2bf_rne(acc[i][j][1] + bias[i][1]);
                unsigned short v2 = f2bf_rne(acc[i][j][2] + bias[i][2]);
                unsigned short v3 = f2bf_rne(acc[i][j][3] + bias[i][3]);
                uint2 st;
                st.x = (unsigned int)v0 | ((unsigned int)v1 << 16);
                st.y = (unsigned int)v2 | ((unsigned int)v3 << 16);
                *(uint2*)&OT[w][nl * 32 + ((og ^ (nl & 7)) << 2)] = st;
            }
        unsigned short* outp = (isQ ? QT : KT) + (size_t)(b * NH + hh) * NPIX * 32;
        #pragma unroll
        for (int it = 0; it < 4; ++it) {
            const int nl = (l >> 2) + 16 * it, seg = l & 3;
            const int g0 = (2 * seg) ^ (nl & 7);
            const int g1 = (2 * seg + 1) ^ (nl & 7);
            const uint2 p0 = *(uint2*)&OT[w][nl * 32 + g0 * 4];
            const uint2 p1 = *(uint2*)&OT[w][nl * 32 + g1 * 4];
            uint4 st; st.x = p0.x; st.y = p0.y; st.z = p1.x; st.w = p1.y;
            *(uint4*)&outp[(size_t)(n0 + nl) * 32 + seg * 8] = st;
        }
    } else {
        const int hh = (o0 - 256) >> 7;
        const int cb = (o0 - 256) & 127;
        unsigned short* vb = V + (size_t)(b * NH + hh) * 128 * NPIX;
        #pragma unroll
        for (int i = 0; i < 2; ++i)
            #pragma unroll
            for (int j = 0; j < 4; ++j)
                #pragma unroll
                for (int r = 0; r < 4; ++r) {
                    const int c = cb + i * 16 + hi * 4 + r;
                    const int n = n0 + j * 16 + lo;
                    vb[(size_t)c * NPIX + n] = f2bf_rne(acc[i][j][r] + bias[i][r]);
                }
    }
}

// ---------------------------------------------------------------------------
// Fused flash attention v3: XCD-grouped blocks, full next-tile register
// prefetch (kf+vf double-buffered), Ps LDS double-buffer, j-interleaved
// softmax->PV, defer-max rescale skip. 4 independent waves/block, 32 q-rows
// per wave, KV tile 64, no barriers.
// ---------------------------------------------------------------------------
__global__ __launch_bounds__(256, 1) void attn(
    const unsigned short* __restrict__ QT, const unsigned short* __restrict__ KT,
    const unsigned short* __restrict__ V,  const float* __restrict__ x,
    const float* __restrict__ gamma, float* __restrict__ out)
{
    __shared__ float SM[4][2176];   // per wave: Ps dbuf 2x4KB bf16  /  Ot 64*33 f
    const int t = threadIdx.x, w = t >> 6, l = t & 63;
    const int lo = l & 15, hi = l >> 4;

    // XCD-grouped decode: linear id u -> XCD u%8; force bh%8 == u%8 so each
    // XCD's K/V working set is 4 bh (1.25 MB, L2-resident).
    const int u = blockIdx.x;              // 0..255
    const int xcd = u & 7;
    const int rr = u >> 3;                 // 0..31
    const int nt = rr & 7;
    const int bh = xcd | ((rr >> 3) << 3);
    const int n0w = nt * 128 + w * 32;

    unsigned short* Ps = (unsigned short*)&SM[w][0];
    float* Ot = &SM[w][0];

    const unsigned short* Qb = QT + (size_t)bh * NPIX * 32;
    const unsigned short* Kb = KT + (size_t)bh * NPIX * 32;
    const unsigned short* Vb = V + (size_t)bh * 128 * NPIX;

    bf16x8 qf[2];
    #pragma unroll
    for (int j = 0; j < 2; ++j)
        qf[j] = *(const bf16x8*)&Qb[(size_t)(n0w + j * 16 + lo) * 32 + hi * 8];

    f32x4 of[2][8] = {};
    float mrow[2] = {-INFINITY, -INFINITY};
    float lrow[2] = {0.f, 0.f};

    bf16x8 kf[2][4], vf[2][8][2];
    // prologue: tile 0
    #pragma unroll
    for (int i = 0; i < 4; ++i)
        kf[0][i] = *(const bf16x8*)&Kb[(size_t)(i * 16 + lo) * 32 + hi * 8];
    #pragma unroll
    for (int c = 0; c < 8; ++c)
        #pragma unroll
        for (int ks = 0; ks < 2; ++ks)
            vf[0][c][ks] = *(const bf16x8*)&Vb[(size_t)(c * 16 + lo) * NPIX + ks * 32 + hi * 8];

    #pragma unroll 2
    for (int tix = 0; tix < 16; ++tix) {
        const int cur = tix & 1, nx = cur ^ 1;
        const int mN = ((tix + 1) & 15) * 64;   // next tile (wraps harmlessly)

        // ---- prefetch next tile's K/V fragments (latency hides under compute)
        #pragma unroll
        for (int i = 0; i < 4; ++i)
            kf[nx][i] = *(const bf16x8*)&Kb[(size_t)(mN + i * 16 + lo) * 32 + hi * 8];
        #pragma unroll
        for (int c = 0; c < 8; ++c)
            #pragma unroll
            for (int ks = 0; ks < 2; ++ks)
                vf[nx][c][ks] = *(const bf16x8*)&Vb[(size_t)(c * 16 + lo) * NPIX + mN + ks * 32 + hi * 8];

        // ---- S^T = mfma(K, Q): D[col=n (lo), rowgrp=m (hi*4+r)]
        const f32x4 zero = {0.f, 0.f, 0.f, 0.f};
        f32x4 sf[4][2];
        #pragma unroll
        for (int i = 0; i < 4; ++i)
            #pragma unroll
            for (int j = 0; j < 2; ++j)
                sf[i][j] = __builtin_amdgcn_mfma_f32_16x16x32_bf16(kf[cur][i], qf[j], zero, 0, 0, 0);

        unsigned short* Pb = Ps + cur * 2048;   // bf16 units; 4KB halves

        float fsc[2]; bool grow[2];
        #pragma unroll
        for (int j = 0; j < 2; ++j) {
            float mx = fmaxf(fmaxf(sf[0][j][0], sf[0][j][1]), fmaxf(sf[0][j][2], sf[0][j][3]));
            #pragma unroll
            for (int i = 1; i < 4; ++i) {
                const float m2 = fmaxf(fmaxf(sf[i][j][0], sf[i][j][1]), fmaxf(sf[i][j][2], sf[i][j][3]));
                mx = fmaxf(mx, m2);
            }
            mx = fmaxf(mx, __shfl_xor(mx, 16));
            mx = fmaxf(mx, __shfl_xor(mx, 32));
            grow[j] = __any(mx > mrow[j]) != 0;
            fsc[j] = 1.f;
            if (grow[j]) {
                const float mn2 = fmaxf(mrow[j], mx);
                fsc[j] = __builtin_amdgcn_exp2f(mrow[j] - mn2);
                mrow[j] = mn2;
            }
            const float mj = mrow[j];
            const int nl = j * 16 + lo;
            float ps = 0.f;
            #pragma unroll
            for (int i = 0; i < 4; ++i) {
                const float p0 = __builtin_amdgcn_exp2f(sf[i][j][0] - mj);
                const float p1 = __builtin_amdgcn_exp2f(sf[i][j][1] - mj);
                const float p2 = __builtin_amdgcn_exp2f(sf[i][j][2] - mj);
                const float p3 = __builtin_amdgcn_exp2f(sf[i][j][3] - mj);
                ps += (p0 + p1) + (p2 + p3);
                const int mchunk = i * 2 + (hi >> 1);
                const int off = nl * 64 + ((mchunk ^ (nl & 7)) << 3) + ((hi & 1) << 2);
                uint2 st; st.x = pack_bf2_trunc(p0, p1); st.y = pack_bf2_trunc(p2, p3);
                *(uint2*)&Pb[off] = st;
            }
            ps += __shfl_xor(ps, 16);
            ps += __shfl_xor(ps, 32);
            lrow[j] = lrow[j] * fsc[j] + ps;
        }

        // ---- PV per inf (rows inf*16+lo were written by j==inf above)
        #pragma unroll
        for (int inf = 0; inf < 2; ++inf) {
            const int nl = inf * 16 + lo;
            bf16x8 pa[2];
            #pragma unroll
            for (int ks = 0; ks < 2; ++ks)
                pa[ks] = *(const bf16x8*)&Pb[nl * 64 + (((ks * 4 + hi) ^ (nl & 7)) << 3)];
            if (grow[inf]) {
                #pragma unroll
                for (int r = 0; r < 4; ++r) {
                    const float f = __shfl(fsc[inf], hi * 4 + r, 16);
                    #pragma unroll
                    for (int c = 0; c < 8; ++c) of[inf][c][r] *= f;
                }
            }
            #pragma unroll
            for (int c = 0; c < 8; ++c) {
                of[inf][c] = __builtin_amdgcn_mfma_f32_16x16x32_bf16(pa[0], vf[cur][c][0], of[inf][c], 0, 0, 0);
                of[inf][c] = __builtin_amdgcn_mfma_f32_16x16x32_bf16(pa[1], vf[cur][c][1], of[inf][c], 0, 0, 0);
            }
        }
    }

    // ---- epilogue: normalize, transpose via LDS, coalesced gamma*o + x
    float invv[2][4];
    #pragma unroll
    for (int inf = 0; inf < 2; ++inf)
        #pragma unroll
        for (int r = 0; r < 4; ++r)
            invv[inf][r] = 1.0f / __shfl(lrow[inf], hi * 4 + r, 16);

    const float g = gamma[0];
    const int b = bh >> 2, h = bh & 3;

    #pragma unroll
    for (int half = 0; half < 2; ++half) {
        #pragma unroll
        for (int inf = 0; inf < 2; ++inf)
            #pragma unroll
            for (int r = 0; r < 4; ++r) {
                const int n = inf * 16 + hi * 4 + r;
                #pragma unroll
                for (int cf = 0; cf < 4; ++cf)
                    Ot[(cf * 16 + lo) * 33 + n] = of[inf][half * 4 + cf][r] * invv[inf][r];
            }
        const size_t cbase = (size_t)b * CH + h * 128 + half * 64;
        #pragma unroll 4
        for (int cc = 0; cc < 32; ++cc) {
            const int cl = (l >> 5) + 2 * cc;
            const int n = l & 31;
            const float o = Ot[cl * 33 + n];
            const size_t gi = (cbase + cl) * NPIX + n0w + n;
            out[gi] = fmaf(g, o, x[gi]);
        }
    }
}

// ---------------------------------------------------------------------------
extern "C" void kernel_launch(void* const* d_in, const int* in_sizes, int n_in,
                              void* d_out, int out_size, void* d_ws, size_t ws_size,
                              hipStream_t stream)
{
    const float* x     = (const float*)d_in[0];
    const float* Wq    = (const float*)d_in[1];
    const float* bq    = (const float*)d_in[2];
    const float* Wk    = (const float*)d_in[3];
    const float* bk    = (const float*)d_in[4];
    const float* Wv    = (const float*)d_in[5];
    const float* bv    = (const float*)d_in[6];
    const float* gamma = (const float*)d_in[7];
    float* out = (float*)d_out;

    char* ws = (char*)d_ws;
    unsigned short* XTp = (unsigned short*)(ws);             // 8 MB
    unsigned short* Wbp = (unsigned short*)(ws + 8388608);   // 768 KB
    unsigned short* QTp = (unsigned short*)(ws + 9175040);   // 2 MB
    unsigned short* KTp = (unsigned short*)(ws + 11272192);  // 2 MB
    unsigned short* Vp  = (unsigned short*)(ws + 13369344);  // 8 MB

    x_transpose<<<dim3(16, 8, 8), 256, 0, stream>>>(x, XTp);
    w_convert<<<dim3(384), 256, 0, stream>>>(Wq, Wk, Wv, Wbp);
    qkv_proj<<<dim3(8, 12, 8), 256, 0, stream>>>(XTp, Wbp, bq, bk, bv, QTp, KTp, Vp);
    attn<<<dim3(256), 256, 0, stream>>>(QTp, KTp, Vp, x, gamma, out);
}